// Round 5
// baseline (143.310 us; speedup 1.0000x reference)
//
#include <hip/hip_runtime.h>

typedef _Float16 half8 __attribute__((ext_vector_type(8)));
typedef _Float16 h16 __attribute__((ext_vector_type(16)));
typedef float f32x4 __attribute__((ext_vector_type(4)));

#define DIN 512
#define DOUT 128
#define BTOT 8192
#define NCHUNK 68                 // 64 spline + 4 skip chunks of BK=128
#define NSPL 16
#define BM 128
#define CHUNK_BYTES 32768         // W chunk: 16 p-slabs x 128 o x 16 B
#define LDS_BYTES 32768           // C tile only: 16 p-slabs x 128 rows x 16 B

__device__ static inline unsigned short f2h(float x) {
  _Float16 h = (_Float16)x;
  return __builtin_bit_cast(unsigned short, h);
}

// ---------------- prep 1: pack W_aug (f16) into [chunk][p][o] granules ----------------
__global__ __launch_bounds__(256) void build_wpp(const float* __restrict__ w,
                                                 const float* __restrict__ sk,
                                                 unsigned short* __restrict__ wpp) {
  const int gid = blockIdx.x * 256 + threadIdx.x;   // < 68*2048
  const int g = gid >> 11;
  const int rem = gid & 2047;
  const int p = rem >> 7;
  const int o = rem & 127;
  const int kglob = g * 128 + p * 8;
  const float* src = (kglob < 8192) ? (w + (size_t)o * 8192 + kglob)
                                    : (sk + (size_t)o * 512 + (kglob - 8192));
  const float4 v0 = ((const float4*)src)[0];
  const float4 v1 = ((const float4*)src)[1];
  uint4 pk;
  pk.x = f2h(v0.x) | ((unsigned)f2h(v0.y) << 16);
  pk.y = f2h(v0.z) | ((unsigned)f2h(v0.w) << 16);
  pk.z = f2h(v1.x) | ((unsigned)f2h(v1.y) << 16);
  pk.w = f2h(v1.z) | ((unsigned)f2h(v1.w) << 16);
  ((uint4*)wpp)[gid] = pk;
}

// ---------------- prep 2: x (8192x512 f32) -> xt (512x8192 f16) ----------------
__global__ __launch_bounds__(256) void xpose(const float* __restrict__ x,
                                             _Float16* __restrict__ xt) {
  __shared__ _Float16 t[32][33];
  const int c0 = blockIdx.x * 32;   // i block
  const int r0 = blockIdx.y * 32;   // b block
  const int tx = threadIdx.x & 31, ty = threadIdx.x >> 5;
#pragma unroll
  for (int j = 0; j < 32; j += 8)
    t[ty + j][tx] = (_Float16)x[(size_t)(r0 + ty + j) * DIN + c0 + tx];
  __syncthreads();
#pragma unroll
  for (int j = 0; j < 32; j += 8)
    xt[(size_t)(c0 + ty + j) * BTOT + r0 + tx] = t[tx][ty + j];
}

// ---------------- main: fused C-build + f16 MFMA, W straight from L2 ----------------
// grid 1024 = 64 b-tiles x 16 k-splits; block 256 = 4 waves, wave-tile 64x64
__global__ __launch_bounds__(256, 4) void kan_mfma(
    const float* __restrict__ x, const _Float16* __restrict__ xt,
    const unsigned short* __restrict__ wpp, const float* __restrict__ bias,
    float* __restrict__ out) {
  __shared__ __align__(16) char smem[LDS_BYTES];  // C tile [p][row], p-slab 2048 B
  const int tid = threadIdx.x;
  const int bt = blockIdx.x >> 4;
  const int sp = blockIdx.x & 15;
  const int b0 = bt * BM;
  const int wid = tid >> 6, lane = tid & 63;
  const int lr = lane & 15, lq = lane >> 4;
  const int wm = wid & 1, wn = wid >> 1;

  const h16 iota16 = {(_Float16)0, (_Float16)1, (_Float16)2, (_Float16)3,
                      (_Float16)4, (_Float16)5, (_Float16)6, (_Float16)7,
                      (_Float16)8, (_Float16)9, (_Float16)10, (_Float16)11,
                      (_Float16)12, (_Float16)13, (_Float16)14, (_Float16)15};
  const h16 one16 = {(_Float16)1, (_Float16)1, (_Float16)1, (_Float16)1,
                     (_Float16)1, (_Float16)1, (_Float16)1, (_Float16)1,
                     (_Float16)1, (_Float16)1, (_Float16)1, (_Float16)1,
                     (_Float16)1, (_Float16)1, (_Float16)1, (_Float16)1};
  const h16 zero16 = {};

  f32x4 acc[4][4] = {};
  const int nch = (sp < 4) ? 5 : 4;

  for (int j = 0; j < nch; ++j) {
    const int g = (j < 4) ? (sp + j * 16) : (64 + sp);
    const bool skipc = (j == 4);

    if (j > 0) __syncthreads();   // all waves done reading previous C tile

    // ---- build C tile: [p][row] granules ----
    if (!skipc) {
      const int ib = g * 8;
#pragma unroll
      for (int hh = 0; hh < 2; ++hh) {
        const int il = wid * 2 + hh;
#pragma unroll
        for (int rh = 0; rh < 2; ++rh) {
          const int r = lane + rh * 64;
          const float xv = (float)xt[(size_t)(ib + il) * BTOT + b0 + r];
          float t = fminf(fmaxf((xv + 3.0f) * (1.0f / 6.0f), 0.0f), 1.0f);
          const _Float16 ph = (_Float16)(t * 15.0f);
          h16 pv;
#pragma unroll
          for (int q = 0; q < 16; ++q) pv[q] = ph;
          h16 d = __builtin_elementwise_abs(pv - iota16);
          h16 cc = __builtin_elementwise_max(one16 - d, zero16);
          char* base = smem + (2 * il) * 2048 + r * 16;
          *(uint4*)base = ((const uint4*)&cc)[0];
          *(uint4*)(base + 2048) = ((const uint4*)&cc)[1];
        }
      }
    } else {
      const int ioff = (g - 64) * 128;
#pragma unroll
      for (int pp = 0; pp < 4; ++pp) {
        const int p = wid * 4 + pp;
#pragma unroll
        for (int rh = 0; rh < 2; ++rh) {
          const int r = lane + rh * 64;
          const float* src = x + (size_t)(b0 + r) * DIN + ioff + p * 8;
          const float4 v0 = ((const float4*)src)[0];
          const float4 v1 = ((const float4*)src)[1];
          uint4 pk;
          pk.x = f2h(v0.x) | ((unsigned)f2h(v0.y) << 16);
          pk.y = f2h(v0.z) | ((unsigned)f2h(v0.w) << 16);
          pk.z = f2h(v1.x) | ((unsigned)f2h(v1.y) << 16);
          pk.w = f2h(v1.z) | ((unsigned)f2h(v1.w) << 16);
          *(uint4*)(smem + p * 2048 + r * 16) = pk;
        }
      }
    }
    __syncthreads();

    // ---- MFMA: B-fragments straight from global (L2-resident wpp) ----
    const char* wchunk = (const char*)wpp + (size_t)g * CHUNK_BYTES
                       + (size_t)lq * 2048 + (size_t)(wn * 64 + lr) * 16;
#pragma unroll
    for (int ks = 0; ks < 4; ++ks) {
      const int slab = (ks * 4 + lq) * 2048 + lr * 16;
      half8 af[4], bf[4];
#pragma unroll
      for (int nt = 0; nt < 4; ++nt)
        bf[nt] = *(const half8*)(wchunk + ks * 8192 + nt * 256);
#pragma unroll
      for (int mt = 0; mt < 4; ++mt)
        af[mt] = *(const half8*)(smem + slab + (wm * 64 + mt * 16) * 16);
#pragma unroll
      for (int mt = 0; mt < 4; ++mt)
#pragma unroll
        for (int nt = 0; nt < 4; ++nt)
          acc[mt][nt] = __builtin_amdgcn_mfma_f32_16x16x32_f16(af[mt], bf[nt], acc[mt][nt], 0, 0, 0);
    }
  }

  // ---- epilogue: atomic accumulate across k-splits; bias on split 0 ----
#pragma unroll
  for (int nt = 0; nt < 4; ++nt) {
    const int col = wn * 64 + nt * 16 + lr;
    const float bv = (sp == 0) ? bias[col] : 0.0f;
#pragma unroll
    for (int mt = 0; mt < 4; ++mt) {
      const int row0 = b0 + wm * 64 + mt * 16 + lq * 4;
#pragma unroll
      for (int r = 0; r < 4; ++r)
        atomicAdd(out + (size_t)(row0 + r) * DOUT + col, acc[mt][nt][r] + bv);
    }
  }
}

// ---------------- safety-net naive kernel (only if ws too small) ----------------
__global__ void kan_naive(const float* __restrict__ x, const float* __restrict__ w,
                          const float* __restrict__ skw, const float* __restrict__ bias,
                          float* __restrict__ out) {
  const int b = blockIdx.x;
  const int o = threadIdx.x;
  float acc = bias[o];
  for (int i = 0; i < DIN; ++i) {
    float xv = x[(size_t)b * DIN + i];
    float t = fminf(fmaxf((xv + 3.0f) * (1.0f / 6.0f), 0.0f), 1.0f);
    float p = t * 15.0f;
    float fi = floorf(p);
    int i0 = (int)fi;
    int i1 = (i0 < 15) ? i0 + 1 : 15;
    float f = p - fi;
    const float* wr = &w[((size_t)o * DIN + i) * 16];
    acc += (1.0f - f) * wr[i0] + f * wr[i1] + xv * skw[(size_t)o * DIN + i];
  }
  out[(size_t)b * DOUT + o] = acc;
}

extern "C" void kernel_launch(void* const* d_in, const int* in_sizes, int n_in,
                              void* d_out, int out_size, void* d_ws, size_t ws_size,
                              hipStream_t stream) {
  const float* x    = (const float*)d_in[0];
  const float* w    = (const float*)d_in[1];  // (128, 512, 16) fp32
  const float* skw  = (const float*)d_in[2];  // (128, 512) fp32
  const float* bias = (const float*)d_in[3];  // (128,) fp32
  float* out = (float*)d_out;                 // (8192, 128) fp32

  const size_t xt_bytes = (size_t)DIN * BTOT * sizeof(_Float16);      // 8 MiB
  const size_t wpp_bytes = (size_t)NCHUNK * CHUNK_BYTES;              // 2.125 MiB
  if (ws_size < xt_bytes + wpp_bytes) {
    kan_naive<<<BTOT, DOUT, 0, stream>>>(x, w, skw, bias, out);
    return;
  }

  _Float16* xt = (_Float16*)d_ws;
  unsigned short* wpp = (unsigned short*)((char*)d_ws + xt_bytes);

  (void)hipMemsetAsync(d_out, 0, (size_t)out_size * sizeof(float), stream);
  build_wpp<<<NCHUNK * 2048 / 256, 256, 0, stream>>>(w, skw, wpp);
  xpose<<<dim3(DIN / 32, BTOT / 32), 256, 0, stream>>>(x, xt);
  kan_mfma<<<(BTOT / BM) * NSPL, 256, 0, stream>>>(x, xt, wpp, bias, out);
}

// Round 6
// 141.696 us; speedup vs baseline: 1.0114x; 1.0114x over previous
//
#include <hip/hip_runtime.h>

typedef _Float16 half8 __attribute__((ext_vector_type(8)));
typedef float f32x16 __attribute__((ext_vector_type(16)));

#define DIN 512
#define DOUT 128
#define BTOT 8192
#define NCHUNK 68                 // 64 spline + 4 skip chunks of BK=128
#define NSPL 17                   // 68/17 = 4 chunks per block, perfectly even
#define BM 128
#define CHUNK_BYTES 32768         // W chunk: 16 p-slabs x 128 o x 16 B
#define LDS_BYTES 32768           // W chunk only

// async global->LDS, 16B/lane (lds dst is wave-uniform; HW adds lane*16)
__device__ static inline void llds16(const char* g, char* l) {
  __builtin_amdgcn_global_load_lds(
      (const __attribute__((address_space(1))) unsigned int*)g,
      (__attribute__((address_space(3))) unsigned int*)l, 16, 0, 0);
}

__device__ static inline unsigned short f2h(float x) {
  _Float16 h = (_Float16)x;
  return __builtin_bit_cast(unsigned short, h);
}

// ---------------- prep 1: pack W_aug (f16) into [chunk][p][o] granules ----------------
__global__ __launch_bounds__(256) void build_wpp(const float* __restrict__ w,
                                                 const float* __restrict__ sk,
                                                 unsigned short* __restrict__ wpp) {
  const int gid = blockIdx.x * 256 + threadIdx.x;   // < 68*2048
  const int g = gid >> 11;
  const int rem = gid & 2047;
  const int p = rem >> 7;
  const int o = rem & 127;
  const int kglob = g * 128 + p * 8;
  const float* src = (kglob < 8192) ? (w + (size_t)o * 8192 + kglob)
                                    : (sk + (size_t)o * 512 + (kglob - 8192));
  const float4 v0 = ((const float4*)src)[0];
  const float4 v1 = ((const float4*)src)[1];
  uint4 pk;
  pk.x = f2h(v0.x) | ((unsigned)f2h(v0.y) << 16);
  pk.y = f2h(v0.z) | ((unsigned)f2h(v0.w) << 16);
  pk.z = f2h(v1.x) | ((unsigned)f2h(v1.y) << 16);
  pk.w = f2h(v1.z) | ((unsigned)f2h(v1.w) << 16);
  ((uint4*)wpp)[gid] = pk;
}

// ---------------- prep 2: xh = f16(x), row-major (no transpose) ----------------
__global__ __launch_bounds__(256) void xcast(const float* __restrict__ x,
                                             _Float16* __restrict__ xh) {
  const int n = (blockIdx.x * 256 + threadIdx.x) * 4;
  const float4 v = *(const float4*)(x + n);
  unsigned lo = f2h(v.x) | ((unsigned)f2h(v.y) << 16);
  unsigned hi = f2h(v.z) | ((unsigned)f2h(v.w) << 16);
  *(uint2*)(xh + n) = make_uint2(lo, hi);
}

// ---------------- main: in-register spline A + 32x32x16 f16 MFMA ----------------
// grid 1088 = 64 b-tiles x 17 k-splits; block 256 = 4 waves (2x2), wave-tile 64x64
__global__ __launch_bounds__(256, 3) void kan_mfma(
    const _Float16* __restrict__ xh, const unsigned short* __restrict__ wpp,
    const float* __restrict__ bias, float* __restrict__ out) {
  __shared__ __align__(16) char smem[LDS_BYTES];   // W chunk [p][o] granules
  const int tid = threadIdx.x;
  const unsigned u = blockIdx.x;
  const int bt = u & 63;          // same-bt splits share blockIdx%8 -> same XCD
  const int sp = u >> 6;          // 0..16
  const int b0 = bt * BM;
  const int wid = tid >> 6, lane = tid & 63;
  const int l5 = lane >> 5, l31 = lane & 31;
  const int wm = wid & 1, wn = wid >> 1;

  half8 iotaA, one8, three8, c6_8, fif8;
  const half8 zero8 = {};
#pragma unroll
  for (int q = 0; q < 8; ++q) {
    iotaA[q] = (_Float16)(l5 * 8 + q);
    one8[q] = (_Float16)1.0f;
    three8[q] = (_Float16)3.0f;
    c6_8[q] = (_Float16)(1.0f / 6.0f);
    fif8[q] = (_Float16)15.0f;
  }

  f32x16 acc[2][2] = {};

#pragma unroll
  for (int j = 0; j < 4; ++j) {
    const int g = sp + j * 17;          // covers 0..67 exactly once over all sp
    const bool spl = (g < 64);

    // A-source prefetch from global (independent of barriers)
    half8 asrc[2];
    if (spl) {
#pragma unroll
      for (int mt = 0; mt < 2; ++mt) {
        const int row = b0 + wm * 64 + mt * 32 + l31;
        asrc[mt] = *(const half8*)(xh + (size_t)row * DIN + g * 8);
      }
    }

    __syncthreads();   // previous chunk's B readers done
    {
      const char* gsrc = (const char*)wpp + (size_t)g * CHUNK_BYTES + wid * 8192 + lane * 16;
      char* ldst = smem + wid * 8192;
#pragma unroll
      for (int it = 0; it < 8; ++it)
        llds16(gsrc + it * 1024, ldst + it * 1024);
    }
    __syncthreads();   // W chunk ready

    if (spl) {
      // pos8 per m-tile (f16 pk math)
      half8 pos[2];
#pragma unroll
      for (int mt = 0; mt < 2; ++mt) {
        half8 a = (asrc[mt] + three8) * c6_8;
        a = __builtin_elementwise_max(a, zero8);
        a = __builtin_elementwise_min(a, one8);
        pos[mt] = a * fif8;
      }
#pragma unroll
      for (int kc = 0; kc < 8; ++kc) {
        half8 bfr[2];
#pragma unroll
        for (int nt = 0; nt < 2; ++nt)
          bfr[nt] = *(const half8*)(smem + (kc * 2 + l5) * 2048 + (wn * 64 + nt * 32 + l31) * 16);
#pragma unroll
        for (int mt = 0; mt < 2; ++mt) {
          const _Float16 p = pos[mt][kc];
          const half8 pv = {p, p, p, p, p, p, p, p};
          const half8 d = __builtin_elementwise_abs(pv - iotaA);
          const half8 cf = __builtin_elementwise_max(one8 - d, zero8);
#pragma unroll
          for (int nt = 0; nt < 2; ++nt)
            acc[mt][nt] = __builtin_amdgcn_mfma_f32_32x32x16_f16(cf, bfr[nt], acc[mt][nt], 0, 0, 0);
        }
      }
    } else {
      const int ioff = (g - 64) * 128;
#pragma unroll
      for (int kc = 0; kc < 8; ++kc) {
        half8 bfr[2];
#pragma unroll
        for (int nt = 0; nt < 2; ++nt)
          bfr[nt] = *(const half8*)(smem + (kc * 2 + l5) * 2048 + (wn * 64 + nt * 32 + l31) * 16);
#pragma unroll
        for (int mt = 0; mt < 2; ++mt) {
          const int row = b0 + wm * 64 + mt * 32 + l31;
          const half8 af = *(const half8*)(xh + (size_t)row * DIN + ioff + kc * 16 + l5 * 8);
#pragma unroll
          for (int nt = 0; nt < 2; ++nt)
            acc[mt][nt] = __builtin_amdgcn_mfma_f32_32x32x16_f16(af, bfr[nt], acc[mt][nt], 0, 0, 0);
        }
      }
    }
  }

  // ---- epilogue: 32x32 C/D layout col=lane&31, row=(r&3)+8*(r>>2)+4*(lane>>5) ----
#pragma unroll
  for (int nt = 0; nt < 2; ++nt) {
    const int col = wn * 64 + nt * 32 + l31;
    const float bv = (sp == 0) ? bias[col] : 0.0f;
#pragma unroll
    for (int mt = 0; mt < 2; ++mt) {
      const int rbase = b0 + wm * 64 + mt * 32 + 4 * l5;
#pragma unroll
      for (int r = 0; r < 16; ++r) {
        const int row = rbase + (r & 3) + 8 * (r >> 2);
        atomicAdd(out + (size_t)row * DOUT + col, acc[mt][nt][r] + bv);
      }
    }
  }
}

// ---------------- safety-net naive kernel (only if ws too small) ----------------
__global__ void kan_naive(const float* __restrict__ x, const float* __restrict__ w,
                          const float* __restrict__ skw, const float* __restrict__ bias,
                          float* __restrict__ out) {
  const int b = blockIdx.x;
  const int o = threadIdx.x;
  float acc = bias[o];
  for (int i = 0; i < DIN; ++i) {
    float xv = x[(size_t)b * DIN + i];
    float t = fminf(fmaxf((xv + 3.0f) * (1.0f / 6.0f), 0.0f), 1.0f);
    float p = t * 15.0f;
    float fi = floorf(p);
    int i0 = (int)fi;
    int i1 = (i0 < 15) ? i0 + 1 : 15;
    float f = p - fi;
    const float* wr = &w[((size_t)o * DIN + i) * 16];
    acc += (1.0f - f) * wr[i0] + f * wr[i1] + xv * skw[(size_t)o * DIN + i];
  }
  out[(size_t)b * DOUT + o] = acc;
}

extern "C" void kernel_launch(void* const* d_in, const int* in_sizes, int n_in,
                              void* d_out, int out_size, void* d_ws, size_t ws_size,
                              hipStream_t stream) {
  const float* x    = (const float*)d_in[0];
  const float* w    = (const float*)d_in[1];  // (128, 512, 16) fp32
  const float* skw  = (const float*)d_in[2];  // (128, 512) fp32
  const float* bias = (const float*)d_in[3];  // (128,) fp32
  float* out = (float*)d_out;                 // (8192, 128) fp32

  const size_t xh_bytes = (size_t)BTOT * DIN * sizeof(_Float16);      // 8 MiB
  const size_t wpp_bytes = (size_t)NCHUNK * CHUNK_BYTES;              // 2.125 MiB
  if (ws_size < xh_bytes + wpp_bytes) {
    kan_naive<<<BTOT, DOUT, 0, stream>>>(x, w, skw, bias, out);
    return;
  }

  _Float16* xh = (_Float16*)d_ws;
  unsigned short* wpp = (unsigned short*)((char*)d_ws + xh_bytes);

  (void)hipMemsetAsync(d_out, 0, (size_t)out_size * sizeof(float), stream);
  build_wpp<<<NCHUNK * 2048 / 256, 256, 0, stream>>>(w, skw, wpp);
  xcast<<<BTOT * DIN / 1024, 256, 0, stream>>>(x, xh);
  kan_mfma<<<(BTOT / BM) * NSPL, 256, 0, stream>>>(xh, wpp, bias, out);
}

// Round 7
// 122.674 us; speedup vs baseline: 1.1682x; 1.1551x over previous
//
#include <hip/hip_runtime.h>

typedef _Float16 half8 __attribute__((ext_vector_type(8)));
typedef float f32x16 __attribute__((ext_vector_type(16)));
typedef float f32x4v __attribute__((ext_vector_type(4)));

#define DIN 512
#define DOUT 128
#define BTOT 8192
#define NCHUNK 68                 // 64 spline + 4 skip chunks of BK=128
#define NSPL 4                    // split-K over augmented K; 17 chunks/block
#define CPB 17
#define BM 128
#define CHUNK_BYTES 32768         // W chunk: 16 p-slabs x 128 o x 16 B
#define LDS_BYTES 65536           // double-buffered W chunk

// async global->LDS, 16B/lane (lds dst is wave-uniform; HW adds lane*16)
__device__ static inline void llds16(const char* g, char* l) {
  __builtin_amdgcn_global_load_lds(
      (const __attribute__((address_space(1))) unsigned int*)g,
      (__attribute__((address_space(3))) unsigned int*)l, 16, 0, 0);
}

__device__ static inline unsigned short f2h(float x) {
  _Float16 h = (_Float16)x;
  return __builtin_bit_cast(unsigned short, h);
}

// ---------------- prep: pack W_aug (f16) into [chunk][p][o] granules ----------------
__global__ __launch_bounds__(256) void build_wpp(const float* __restrict__ w,
                                                 const float* __restrict__ sk,
                                                 unsigned short* __restrict__ wpp) {
  const int gid = blockIdx.x * 256 + threadIdx.x;   // < 68*2048
  const int g = gid >> 11;
  const int rem = gid & 2047;
  const int p = rem >> 7;
  const int o = rem & 127;
  const int kglob = g * 128 + p * 8;
  const float* src = (kglob < 8192) ? (w + (size_t)o * 8192 + kglob)
                                    : (sk + (size_t)o * 512 + (kglob - 8192));
  const float4 v0 = ((const float4*)src)[0];
  const float4 v1 = ((const float4*)src)[1];
  uint4 pk;
  pk.x = f2h(v0.x) | ((unsigned)f2h(v0.y) << 16);
  pk.y = f2h(v0.z) | ((unsigned)f2h(v0.w) << 16);
  pk.z = f2h(v1.x) | ((unsigned)f2h(v1.y) << 16);
  pk.w = f2h(v1.z) | ((unsigned)f2h(v1.w) << 16);
  ((uint4*)wpp)[gid] = pk;
}

// ---------------- main: in-register spline A + 32x32x16 f16 MFMA, partials out ----------------
// grid 256 = 64 b-tiles x 4 k-splits; block 256 = 4 waves (2x2), wave-tile 64x64
__global__ __launch_bounds__(256) void kan_mfma(
    const float* __restrict__ x, const unsigned short* __restrict__ wpp,
    float* __restrict__ part) {
  __shared__ __align__(16) char smem[LDS_BYTES];   // 2 x 32 KiB W-chunk buffers
  const int tid = threadIdx.x;
  const int bt = blockIdx.x >> 2;
  const int sp = blockIdx.x & 3;
  const int b0 = bt * BM;
  const int wid = tid >> 6, lane = tid & 63;
  const int l5 = lane >> 5, l31 = lane & 31;
  const int wm = wid & 1, wn = wid >> 1;

  half8 iotaA, one8;
  const half8 zero8 = {};
#pragma unroll
  for (int q = 0; q < 8; ++q) {
    iotaA[q] = (_Float16)(l5 * 8 + q);
    one8[q] = (_Float16)1.0f;
  }

  // stage chunk j (g = j*4+sp) into buffer buf
  auto stage = [&](int j, int buf) {
    const int g = j * 4 + sp;
    const char* gsrc = (const char*)wpp + (size_t)g * CHUNK_BYTES + wid * 8192 + lane * 16;
    char* ldst = smem + buf * CHUNK_BYTES + wid * 8192;
#pragma unroll
    for (int it = 0; it < 8; ++it)
      llds16(gsrc + it * 1024, ldst + it * 1024);
  };

  f32x16 acc[2][2] = {};

  stage(0, 0);

  // ---- spline chunks: j = 0..15, g = j*4+sp in [0,64) ----
  for (int j = 0; j < 16; ++j) {
    __syncthreads();                      // drains stage(j) DMA; syncs readers of buf[j-1&1]
    stage(j + 1, (j + 1) & 1);            // in flight during compute of chunk j
    const char* buf = smem + (j & 1) * CHUNK_BYTES;
    const int g = j * 4 + sp;

    float pos[2][8];
#pragma unroll
    for (int mt = 0; mt < 2; ++mt) {
      const int row = b0 + wm * 64 + mt * 32 + l31;
      const float* src = x + (size_t)row * DIN + g * 8;
      const float4 v0 = ((const float4*)src)[0];
      const float4 v1 = ((const float4*)src)[1];
      const float xv[8] = {v0.x, v0.y, v0.z, v0.w, v1.x, v1.y, v1.z, v1.w};
#pragma unroll
      for (int q = 0; q < 8; ++q) {
        const float t = fminf(fmaxf((xv[q] + 3.0f) * (1.0f / 6.0f), 0.0f), 1.0f);
        pos[mt][q] = t * 15.0f;
      }
    }
#pragma unroll
    for (int kc = 0; kc < 8; ++kc) {
      half8 bfr[2];
#pragma unroll
      for (int nt = 0; nt < 2; ++nt)
        bfr[nt] = *(const half8*)(buf + (kc * 2 + l5) * 2048 + (wn * 64 + nt * 32 + l31) * 16);
#pragma unroll
      for (int mt = 0; mt < 2; ++mt) {
        const _Float16 p = (_Float16)pos[mt][kc];
        const half8 pv = {p, p, p, p, p, p, p, p};
        const half8 d = __builtin_elementwise_abs(pv - iotaA);
        const half8 cf = __builtin_elementwise_max(one8 - d, zero8);
#pragma unroll
        for (int nt = 0; nt < 2; ++nt)
          acc[mt][nt] = __builtin_amdgcn_mfma_f32_32x32x16_f16(cf, bfr[nt], acc[mt][nt], 0, 0, 0);
      }
    }
  }

  // ---- skip chunk: j = 16, g = 64+sp, buffer 0 ----
  {
    __syncthreads();
    const char* buf = smem;               // 16 & 1 == 0
    const int ioff = sp * 128;            // (g-64)*128
#pragma unroll
    for (int kc = 0; kc < 8; ++kc) {
      half8 bfr[2];
#pragma unroll
      for (int nt = 0; nt < 2; ++nt)
        bfr[nt] = *(const half8*)(buf + (kc * 2 + l5) * 2048 + (wn * 64 + nt * 32 + l31) * 16);
#pragma unroll
      for (int mt = 0; mt < 2; ++mt) {
        const int row = b0 + wm * 64 + mt * 32 + l31;
        const float* src = x + (size_t)row * DIN + ioff + kc * 16 + l5 * 8;
        const float4 v0 = ((const float4*)src)[0];
        const float4 v1 = ((const float4*)src)[1];
        const half8 af = {(_Float16)v0.x, (_Float16)v0.y, (_Float16)v0.z, (_Float16)v0.w,
                          (_Float16)v1.x, (_Float16)v1.y, (_Float16)v1.z, (_Float16)v1.w};
#pragma unroll
        for (int nt = 0; nt < 2; ++nt)
          acc[mt][nt] = __builtin_amdgcn_mfma_f32_32x32x16_f16(af, bfr[nt], acc[mt][nt], 0, 0, 0);
      }
    }
  }

  // ---- epilogue: plain stores of f32 partials (no atomics) ----
  float* pb = part + (size_t)sp * (BTOT * DOUT);
#pragma unroll
  for (int nt = 0; nt < 2; ++nt) {
    const int col = wn * 64 + nt * 32 + l31;
#pragma unroll
    for (int mt = 0; mt < 2; ++mt) {
      const int rbase = b0 + wm * 64 + mt * 32 + 4 * l5;
#pragma unroll
      for (int r = 0; r < 16; ++r) {
        const int row = rbase + (r & 3) + 8 * (r >> 2);
        pb[(size_t)row * DOUT + col] = acc[mt][nt][r];
      }
    }
  }
}

// ---------------- reduce: out = bias + sum_sp part[sp] ----------------
__global__ __launch_bounds__(256) void kan_reduce(const float* __restrict__ part,
                                                  const float* __restrict__ bias,
                                                  float* __restrict__ out) {
  const int n = (blockIdx.x * 256 + threadIdx.x) * 4;
  f32x4v s = *(const f32x4v*)(bias + (n & 127));
#pragma unroll
  for (int sp = 0; sp < 4; ++sp)
    s += *(const f32x4v*)(part + (size_t)sp * (BTOT * DOUT) + n);
  *(f32x4v*)(out + n) = s;
}

// ---------------- safety-net naive kernel (only if ws too small) ----------------
__global__ void kan_naive(const float* __restrict__ x, const float* __restrict__ w,
                          const float* __restrict__ skw, const float* __restrict__ bias,
                          float* __restrict__ out) {
  const int b = blockIdx.x;
  const int o = threadIdx.x;
  float acc = bias[o];
  for (int i = 0; i < DIN; ++i) {
    float xv = x[(size_t)b * DIN + i];
    float t = fminf(fmaxf((xv + 3.0f) * (1.0f / 6.0f), 0.0f), 1.0f);
    float p = t * 15.0f;
    float fi = floorf(p);
    int i0 = (int)fi;
    int i1 = (i0 < 15) ? i0 + 1 : 15;
    float f = p - fi;
    const float* wr = &w[((size_t)o * DIN + i) * 16];
    acc += (1.0f - f) * wr[i0] + f * wr[i1] + xv * skw[(size_t)o * DIN + i];
  }
  out[(size_t)b * DOUT + o] = acc;
}

extern "C" void kernel_launch(void* const* d_in, const int* in_sizes, int n_in,
                              void* d_out, int out_size, void* d_ws, size_t ws_size,
                              hipStream_t stream) {
  const float* x    = (const float*)d_in[0];
  const float* w    = (const float*)d_in[1];  // (128, 512, 16) fp32
  const float* skw  = (const float*)d_in[2];  // (128, 512) fp32
  const float* bias = (const float*)d_in[3];  // (128,) fp32
  float* out = (float*)d_out;                 // (8192, 128) fp32

  const size_t wpp_bytes  = (size_t)NCHUNK * CHUNK_BYTES;               // 2.125 MiB
  const size_t part_bytes = (size_t)NSPL * BTOT * DOUT * sizeof(float); // 16 MiB
  if (ws_size < wpp_bytes + part_bytes) {
    kan_naive<<<BTOT, DOUT, 0, stream>>>(x, w, skw, bias, out);
    return;
  }

  unsigned short* wpp = (unsigned short*)d_ws;
  float* part = (float*)((char*)d_ws + wpp_bytes);

  build_wpp<<<NCHUNK * 2048 / 256, 256, 0, stream>>>(w, skw, wpp);
  kan_mfma<<<(BTOT / BM) * NSPL, 256, 0, stream>>>(x, wpp, part);
  kan_reduce<<<BTOT * DOUT / 1024, 256, 0, stream>>>(part, bias, out);
}